// Round 6
// baseline (2907.903 us; speedup 1.0000x reference)
//
#include <hip/hip_runtime.h>

#define DEVI __device__ __forceinline__
typedef float f2 __attribute__((ext_vector_type(2)));

// ---------------- problem constants ----------------
constexpr int T_ = 4096, B_ = 128;
constexpr int CH = 8, NCH = T_ / CH;   // 512 chunks of 8 timesteps
constexpr int NSTEP = NCH + 32;        // layer l has lag l+1; last store s=542
constexpr int XROW = 68;               // x row padded 64->68 dwords

// LDS ring strides (floats). y1/xw row: sl*Y1S + tt*Y1T + g*20 + j
constexpr int Y1T = 60, Y1S = CH * Y1T, Y1L = 2 * Y1S;
constexpr int Y2T = 36, Y2S = CH * Y2T, Y2L = 2 * Y2S;

struct P {
  const float* x;
  const float* w1; const float* b1;    // wih0 (20x64), bih0 (20)
  const float* wih[31]; const float* whh[31];
  const float* bih[31]; const float* bhh[31];
  float* out;
};

DEVI float ftanh(float x) {
  // tanh(x) = 1 - 2/(exp2(2*log2e*x)+1); ~1ulp, maps +-Inf -> +-1
  float e = __builtin_amdgcn_exp2f(x * 2.8853900817779268f);
  return 1.0f - 2.0f * __builtin_amdgcn_rcpf(e + 1.0f);
}

DEVI f2 pfma(f2 a, f2 b, f2 c) { return __builtin_elementwise_fma(a, b, c); }

DEVI void acc20(f2& a, const float* r, const f2* w) {
#pragma unroll
  for (int q = 0; q < 5; q++) {
    float4 v = ((const float4*)r)[q];
    union { float4 f; f2 h[2]; } u; u.f = v;
    a = pfma(u.h[0], w[2 * q], a);
    a = pfma(u.h[1], w[2 * q + 1], a);
  }
}

DEVI void acc10(f2& a, const float* r, const f2* w) {
  float4 v0 = ((const float4*)r)[0];
  float4 v1 = ((const float4*)r)[1];
  float2 v2 = *(const float2*)(r + 8);
  union { float4 f; f2 h[2]; } u0, u1; u0.f = v0; u1.f = v1;
  f2 t; t.x = v2.x; t.y = v2.y;
  a = pfma(u0.h[0], w[0], a);
  a = pfma(u0.h[1], w[1], a);
  a = pfma(u1.h[0], w[2], a);
  a = pfma(u1.h[1], w[3], a);
  a = pfma(t, w[4], a);
}

// ===== wave 0: global->LDS x staging, register double-buffered =====
DEVI void stage_x(const P& p, int wg, int lane, float* xb) {
  const float* src[6]; int dst[6];
#pragma unroll
  for (int r = 0; r < 6; r++) {
    int f = lane + 64 * r;             // 384 float4 per chunk
    int tq = f / 48, rem = f % 48, gg = rem / 16, qq = rem % 16;
    int b = wg * 3 + gg; if (b > B_ - 1) b = B_ - 1;
    src[r] = p.x + (size_t)(tq * B_ + b) * 64 + qq * 4;
    dst[r] = (tq * 3 + gg) * XROW + qq * 4;
  }
  float4 pf[6];
#pragma unroll
  for (int r = 0; r < 6; r++) pf[r] = *(const float4*)src[r];     // chunk 0
#pragma unroll
  for (int r = 0; r < 6; r++) *(float4*)(xb + dst[r]) = pf[r];    // -> slot 0
#pragma unroll
  for (int r = 0; r < 6; r++) src[r] += (size_t)CH * B_ * 64;
#pragma unroll
  for (int r = 0; r < 6; r++) pf[r] = *(const float4*)src[r];     // chunk 1
#pragma unroll
  for (int r = 0; r < 6; r++) src[r] += (size_t)CH * B_ * 64;

  __syncthreads();
  for (int s = 0; s < NSTEP; s++) {
    const int c = s;
    if (c + 1 < NCH) {
      float* db = xb + ((c + 1) & 1) * (CH * 3 * XROW);
#pragma unroll
      for (int r = 0; r < 6; r++) *(float4*)(db + dst[r]) = pf[r];
      if (c + 2 < NCH) {
#pragma unroll
        for (int r = 0; r < 6; r++) pf[r] = *(const float4*)src[r];
#pragma unroll
        for (int r = 0; r < 6; r++) src[r] += (size_t)CH * B_ * 64;
      }
    }
    __syncthreads();
  }
}

// ===== wave 1: input projection (64 -> 20), lag 0 =====
DEVI void proj(const P& p, int lane, const float* xb, float* xw) {
  const int g = (lane < 60) ? lane / 20 : 2;
  const int j = lane % 20;
  const bool wr = lane < 60;
  f2 wp[32];
#pragma unroll
  for (int k = 0; k < 32; k++) {
    wp[k].x = p.w1[j * 64 + 2 * k]; wp[k].y = p.w1[j * 64 + 2 * k + 1];
  }
  const float bp = p.b1[j];

  __syncthreads();
  for (int s = 0; s < NSTEP; s++) {
    const int c = s;
    if (c < NCH) {
      const int sl = c & 1;
      const float* base = xb + sl * (CH * 3 * XROW) + g * XROW;
      float* ob = xw + sl * Y1S + g * 20 + j;
      for (int tt = 0; tt < CH; tt++) {
        const float* xr = base + tt * (3 * XROW);
        f2 a; a.x = bp; a.y = 0.f;
        f2 b; b.x = 0.f; b.y = 0.f;
#pragma unroll
        for (int q = 0; q < 8; q++) {
          float4 v0 = ((const float4*)xr)[2 * q];
          float4 v1 = ((const float4*)xr)[2 * q + 1];
          union { float4 f; f2 h[2]; } u0, u1; u0.f = v0; u1.f = v1;
          a = pfma(u0.h[0], wp[4 * q + 0], a);
          b = pfma(u0.h[1], wp[4 * q + 1], b);
          a = pfma(u1.h[0], wp[4 * q + 2], a);
          b = pfma(u1.h[1], wp[4 * q + 3], b);
        }
        if (wr) ob[tt * Y1T] = (a.x + b.x) + (a.y + b.y);
      }
    }
    __syncthreads();
  }
}

// ===== waves 2..11: two H=20 layers, chunk-lagged (A: lag la+1, B: lag la+2)
template <bool FIRST>
DEVI void pair(int la, const P& p, int lane, float* y1f, const float* xw) {
  const int g = (lane < 60) ? lane / 20 : 2;
  const int j = lane % 20;
  const bool wr = lane < 60;
  const int lb = la + 1, dA = la + 1, dB = la + 2;
  f2 whA[10], whB[10], wiB[10], wiA[FIRST ? 1 : 10];
#pragma unroll
  for (int k = 0; k < 10; k++) {
    whA[k].x = p.whh[la][j * 20 + 2 * k]; whA[k].y = p.whh[la][j * 20 + 2 * k + 1];
    whB[k].x = p.whh[lb][j * 20 + 2 * k]; whB[k].y = p.whh[lb][j * 20 + 2 * k + 1];
    wiB[k].x = p.wih[lb][j * 20 + 2 * k]; wiB[k].y = p.wih[lb][j * 20 + 2 * k + 1];
  }
  if constexpr (!FIRST) {
#pragma unroll
    for (int k = 0; k < 10; k++) {
      wiA[k].x = p.wih[la][j * 20 + 2 * k]; wiA[k].y = p.wih[la][j * 20 + 2 * k + 1];
    }
  }
  float bA = p.bhh[la][j];
  if constexpr (!FIRST) bA += p.bih[la][j];   // L0: bih folded into projection
  const float bB = p.bih[lb][j] + p.bhh[lb][j];

  const float* yin = FIRST ? (xw + g * 20 + j) : (y1f + (la - 1) * Y1L + g * 20);
  const float* yAr = y1f + la * Y1L + g * 20;
  float*       yAw = y1f + la * Y1L + g * 20 + j;
  const float* yBr = y1f + lb * Y1L + g * 20;
  float*       yBw = y1f + lb * Y1L + g * 20 + j;
  if (wr) {  // h_{-1} = 0 rows (read at c==0, tt==0)
    yAw[Y1S + (CH - 1) * Y1T] = 0.f; yBw[Y1S + (CH - 1) * Y1T] = 0.f;
  }

  __syncthreads();
  for (int s = 0; s < NSTEP; s++) {
    if ((unsigned)(s - dA) <= (unsigned)NCH) {
      const int cA = s - dA, cB = s - dB;
      const int slA = cA & 1, slB = cB & 1;
      const bool wrA = wr && ((unsigned)cA < (unsigned)NCH);
      const bool wrB = wr && ((unsigned)cB < (unsigned)NCH);
      const int SA = slA * Y1S, SB = slB * Y1S;
      int pvA = (1 - slA) * Y1S + (CH - 1) * Y1T;
      int pvB = (1 - slB) * Y1S + (CH - 1) * Y1T;
      for (int tt = 0; tt < CH; tt++) {
        const int inA = SA + tt * Y1T, inB = SB + tt * Y1T;
        // layer A, chunk cA — independent of layer B below (different chunk)
        f2 a1; a1.x = bA; a1.y = 0.f;
        if constexpr (FIRST) a1.x += yin[inA];
        else acc20(a1, yin + inA, wiA);
        f2 a2; a2.x = 0.f; a2.y = 0.f;
        acc20(a2, yAr + pvA, whA);
        const float hA = ftanh((a1.x + a2.x) + (a1.y + a2.y));
        if (wrA) yAw[inA] = hA;
        pvA = inA;
        // layer B, chunk cB = cA-1 (reads A's previous-slot rows)
        f2 b1; b1.x = bB; b1.y = 0.f;
        acc20(b1, yAr + inB, wiB);
        f2 b2; b2.x = 0.f; b2.y = 0.f;
        acc20(b2, yBr + pvB, whB);
        const float hB = ftanh((b1.x + b2.x) + (b1.y + b2.y));
        if (wrB) yBw[inB] = hB;
        pvB = inB;
      }
    }
    __syncthreads();
  }
}

// ===== wave 12: L20 (20->10) lag 21, L21 lag 22, L22 lag 23 =====
DEVI void tri20(const P& p, int lane, const float* y1f, float* y2f) {
  const int g = (lane < 60) ? lane / 20 : 2;
  const int j = lane % 20;
  const int jc = j < 10 ? j : 9;
  const bool wrl = (lane < 60) && (j < 10);
  f2 wi0[10], wh0[5], wi1[5], wh1[5], wi2[5], wh2[5];
#pragma unroll
  for (int k = 0; k < 10; k++) {
    wi0[k].x = p.wih[20][jc * 20 + 2 * k]; wi0[k].y = p.wih[20][jc * 20 + 2 * k + 1];
  }
#pragma unroll
  for (int k = 0; k < 5; k++) {
    wh0[k].x = p.whh[20][jc * 10 + 2 * k]; wh0[k].y = p.whh[20][jc * 10 + 2 * k + 1];
    wi1[k].x = p.wih[21][jc * 10 + 2 * k]; wi1[k].y = p.wih[21][jc * 10 + 2 * k + 1];
    wh1[k].x = p.whh[21][jc * 10 + 2 * k]; wh1[k].y = p.whh[21][jc * 10 + 2 * k + 1];
    wi2[k].x = p.wih[22][jc * 10 + 2 * k]; wi2[k].y = p.wih[22][jc * 10 + 2 * k + 1];
    wh2[k].x = p.whh[22][jc * 10 + 2 * k]; wh2[k].y = p.whh[22][jc * 10 + 2 * k + 1];
  }
  const float b0 = p.bih[20][jc] + p.bhh[20][jc];
  const float b1 = p.bih[21][jc] + p.bhh[21][jc];
  const float b2 = p.bih[22][jc] + p.bhh[22][jc];

  const float* y19 = y1f + 19 * Y1L + g * 20;
  const float* r0 = y2f + 0 * Y2L + g * 12;  float* w0 = y2f + 0 * Y2L + g * 12 + j;
  const float* r1 = y2f + 1 * Y2L + g * 12;  float* w1 = y2f + 1 * Y2L + g * 12 + j;
  const float* r2 = y2f + 2 * Y2L + g * 12;  float* w2 = y2f + 2 * Y2L + g * 12 + j;
  if (wrl) {
    w0[Y2S + (CH - 1) * Y2T] = 0.f; w1[Y2S + (CH - 1) * Y2T] = 0.f;
    w2[Y2S + (CH - 1) * Y2T] = 0.f;
  }

  __syncthreads();
  for (int s = 0; s < NSTEP; s++) {
    if ((unsigned)(s - 21) <= (unsigned)(NCH + 1)) {
      const int c0 = s - 21, c1 = s - 22, c2 = s - 23;
      const int sl0 = c0 & 1, sl1 = c1 & 1, sl2 = c2 & 1;
      const bool g0 = wrl && ((unsigned)c0 < (unsigned)NCH);
      const bool g1 = wrl && ((unsigned)c1 < (unsigned)NCH);
      const bool g2 = wrl && ((unsigned)c2 < (unsigned)NCH);
      int pv0 = (1 - sl0) * Y2S + (CH - 1) * Y2T;
      int pv1 = (1 - sl1) * Y2S + (CH - 1) * Y2T;
      int pv2 = (1 - sl2) * Y2S + (CH - 1) * Y2T;
      for (int tt = 0; tt < CH; tt++) {
        const int in1 = sl0 * Y1S + tt * Y1T;
        const int o0 = sl0 * Y2S + tt * Y2T;
        const int o1 = sl1 * Y2S + tt * Y2T;
        const int o2 = sl2 * Y2S + tt * Y2T;
        f2 a1; a1.x = b0; a1.y = 0.f;
        acc20(a1, y19 + in1, wi0);
        f2 a2; a2.x = 0.f; a2.y = 0.f;
        acc10(a2, r0 + pv0, wh0);
        float h = ftanh((a1.x + a2.x) + (a1.y + a2.y));
        if (g0) w0[o0] = h;
        pv0 = o0;
        f2 c1v; c1v.x = b1; c1v.y = 0.f;
        acc10(c1v, r0 + o1, wi1);
        f2 c2v; c2v.x = 0.f; c2v.y = 0.f;
        acc10(c2v, r1 + pv1, wh1);
        h = ftanh((c1v.x + c2v.x) + (c1v.y + c2v.y));
        if (g1) w1[o1] = h;
        pv1 = o1;
        f2 d1; d1.x = b2; d1.y = 0.f;
        acc10(d1, r1 + o2, wi2);
        f2 d2; d2.x = 0.f; d2.y = 0.f;
        acc10(d2, r2 + pv2, wh2);
        h = ftanh((d1.x + d2.x) + (d1.y + d2.y));
        if (g2) w2[o2] = h;
        pv2 = o2;
      }
    }
    __syncthreads();
  }
}

// ===== waves 13/14: three H=10 layers l0..l0+2, lags l0+1..l0+3 =====
DEVI void tri_s2(int l0, const P& p, int lane, float* y2f) {
  const int g = (lane < 60) ? lane / 20 : 2;
  const int j = lane % 20;
  const int jc = j < 10 ? j : 9;
  const bool wrl = (lane < 60) && (j < 10);
  f2 wi[3][5], wh[3][5];
  float bs[3];
#pragma unroll
  for (int m = 0; m < 3; m++) {
    const int l = l0 + m;
#pragma unroll
    for (int k = 0; k < 5; k++) {
      wi[m][k].x = p.wih[l][jc * 10 + 2 * k]; wi[m][k].y = p.wih[l][jc * 10 + 2 * k + 1];
      wh[m][k].x = p.whh[l][jc * 10 + 2 * k]; wh[m][k].y = p.whh[l][jc * 10 + 2 * k + 1];
    }
    bs[m] = p.bih[l][jc] + p.bhh[l][jc];
  }
  const int bi = l0 - 21;
  const float* yi0 = y2f + bi * Y2L + g * 12;
  const float* r0 = y2f + (bi + 1) * Y2L + g * 12;  float* w0 = y2f + (bi + 1) * Y2L + g * 12 + j;
  const float* r1 = y2f + (bi + 2) * Y2L + g * 12;  float* w1 = y2f + (bi + 2) * Y2L + g * 12 + j;
  const float* r2 = y2f + (bi + 3) * Y2L + g * 12;  float* w2 = y2f + (bi + 3) * Y2L + g * 12 + j;
  if (wrl) {
    w0[Y2S + (CH - 1) * Y2T] = 0.f; w1[Y2S + (CH - 1) * Y2T] = 0.f;
    w2[Y2S + (CH - 1) * Y2T] = 0.f;
  }
  const int d0 = l0 + 1;

  __syncthreads();
  for (int s = 0; s < NSTEP; s++) {
    if ((unsigned)(s - d0) <= (unsigned)(NCH + 1)) {
      const int c0 = s - d0, c1 = c0 - 1, c2 = c0 - 2;
      const int sl0 = c0 & 1, sl1 = c1 & 1, sl2 = c2 & 1;
      const bool g0 = wrl && ((unsigned)c0 < (unsigned)NCH);
      const bool g1 = wrl && ((unsigned)c1 < (unsigned)NCH);
      const bool g2 = wrl && ((unsigned)c2 < (unsigned)NCH);
      int pv0 = (1 - sl0) * Y2S + (CH - 1) * Y2T;
      int pv1 = (1 - sl1) * Y2S + (CH - 1) * Y2T;
      int pv2 = (1 - sl2) * Y2S + (CH - 1) * Y2T;
      for (int tt = 0; tt < CH; tt++) {
        const int o0 = sl0 * Y2S + tt * Y2T;
        const int o1 = sl1 * Y2S + tt * Y2T;
        const int o2 = sl2 * Y2S + tt * Y2T;
        f2 a1; a1.x = bs[0]; a1.y = 0.f;
        acc10(a1, yi0 + o0, wi[0]);
        f2 a2; a2.x = 0.f; a2.y = 0.f;
        acc10(a2, r0 + pv0, wh[0]);
        float h = ftanh((a1.x + a2.x) + (a1.y + a2.y));
        if (g0) w0[o0] = h;
        pv0 = o0;
        f2 b1; b1.x = bs[1]; b1.y = 0.f;
        acc10(b1, r0 + o1, wi[1]);
        f2 b2; b2.x = 0.f; b2.y = 0.f;
        acc10(b2, r1 + pv1, wh[1]);
        h = ftanh((b1.x + b2.x) + (b1.y + b2.y));
        if (g1) w1[o1] = h;
        pv1 = o1;
        f2 e1; e1.x = bs[2]; e1.y = 0.f;
        acc10(e1, r1 + o2, wi[2]);
        f2 e2; e2.x = 0.f; e2.y = 0.f;
        acc10(e2, r2 + pv2, wh[2]);
        h = ftanh((e1.x + e2.x) + (e1.y + e2.y));
        if (g2) w2[o2] = h;
        pv2 = o2;
      }
    }
    __syncthreads();
  }
}

// ===== wave 15: L29 (H=10, lag 30) + L30 (H=1, lag 31) + stores =====
DEVI void tail(const P& p, int wg, int lane, float* y2f) {
  const int g = (lane < 60) ? lane / 20 : 2;
  const int j = lane % 20;
  const int jc = j < 10 ? j : 9;
  const bool wrl = (lane < 60) && (j < 10);
  const int b = wg * 3 + g;
  const bool st = (lane < 60) && (j == 0) && (b < B_);
  f2 wi29[5], wh29[5], wi30[5];
#pragma unroll
  for (int k = 0; k < 5; k++) {
    wi29[k].x = p.wih[29][jc * 10 + 2 * k]; wi29[k].y = p.wih[29][jc * 10 + 2 * k + 1];
    wh29[k].x = p.whh[29][jc * 10 + 2 * k]; wh29[k].y = p.whh[29][jc * 10 + 2 * k + 1];
    wi30[k].x = p.wih[30][2 * k];           wi30[k].y = p.wih[30][2 * k + 1];
  }
  const float b29 = p.bih[29][jc] + p.bhh[29][jc];
  const float b30 = p.bih[30][0] + p.bhh[30][0];
  const float wh30 = p.whh[30][0];
  float h30 = 0.0f;
  const float* r8 = y2f + 8 * Y2L + g * 12;
  const float* r9 = y2f + 9 * Y2L + g * 12;
  float*       w9 = y2f + 9 * Y2L + g * 12 + j;
  if (wrl) w9[Y2S + (CH - 1) * Y2T] = 0.f;
  const int bc = (b < B_) ? b : (B_ - 1);

  __syncthreads();
  for (int s = 0; s < NSTEP; s++) {
    if ((unsigned)(s - 30) <= (unsigned)(NCH)) {
      const int c29 = s - 30, c30 = s - 31;
      const int sl29 = c29 & 1, sl30 = c30 & 1;
      const bool g29 = wrl && ((unsigned)c29 < (unsigned)NCH);
      const bool a30 = (unsigned)c30 < (unsigned)NCH;
      const bool st30 = st && a30;
      int pv = (1 - sl29) * Y2S + (CH - 1) * Y2T;
      float* ob = p.out + (size_t)c30 * CH * B_ + bc;
      for (int tt = 0; tt < CH; tt++) {
        const int o29 = sl29 * Y2S + tt * Y2T;
        const int o30 = sl30 * Y2S + tt * Y2T;
        f2 a1; a1.x = b29; a1.y = 0.f;
        acc10(a1, r8 + o29, wi29);
        f2 a2; a2.x = 0.f; a2.y = 0.f;
        acc10(a2, r9 + pv, wh29);
        const float h = ftanh((a1.x + a2.x) + (a1.y + a2.y));
        if (g29) w9[o29] = h;
        pv = o29;
        f2 a3; a3.x = b30; a3.y = 0.f;
        acc10(a3, r9 + o30, wi30);
        const float h30n = ftanh(fmaf(h30, wh30, a3.x + a3.y));
        h30 = a30 ? h30n : h30;
        if (st30) ob[tt * B_] = h30;
      }
    }
    __syncthreads();
  }
  if (st) p.out[T_ * B_ + b] = h30;  // hT
}

// ================= kernel =================
__global__ __launch_bounds__(1024, 4) void rnn_fused(P p) {
  __shared__ float xbuf[2 * CH * 3 * XROW];   // 13.1 KB staged x
  __shared__ float xw[Y1L];                   //  3.8 KB projected input ring
  __shared__ float y1[20 * Y1L];              // 76.8 KB stack1 rings
  __shared__ float y2[10 * Y2L];              // 23.0 KB stack2 rings
  const int w = threadIdx.x >> 6, lane = threadIdx.x & 63, wg = blockIdx.x;
  if (w == 0)       stage_x(p, wg, lane, xbuf);
  else if (w == 1)  proj(p, lane, xbuf, xw);
  else if (w == 2)  pair<true>(0, p, lane, y1, xw);
  else if (w <= 11) pair<false>(2 * (w - 2), p, lane, y1, xw);
  else if (w == 12) tri20(p, lane, y1, y2);
  else if (w == 13) tri_s2(23, p, lane, y2);
  else if (w == 14) tri_s2(26, p, lane, y2);
  else              tail(p, wg, lane, y2);
}

extern "C" void kernel_launch(void* const* d_in, const int* in_sizes, int n_in,
                              void* d_out, int out_size, void* d_ws, size_t ws_size,
                              hipStream_t stream) {
  (void)in_sizes; (void)out_size; (void)d_ws; (void)ws_size;
  if (n_in < 21) return;
  P p{};
  p.x  = (const float*)d_in[0];
  p.w1 = (const float*)d_in[1];    // s1_wih0 (20x64)
  p.b1 = (const float*)d_in[3];    // s1_bih0
  p.wih[0] = nullptr;              p.whh[0] = (const float*)d_in[2];
  p.bih[0] = nullptr;              p.bhh[0] = (const float*)d_in[4];
  for (int l = 1; l < 20; l++) {
    p.wih[l] = (const float*)d_in[5] + (l - 1) * 400;
    p.whh[l] = (const float*)d_in[6] + (l - 1) * 400;
    p.bih[l] = (const float*)d_in[7] + (l - 1) * 20;
    p.bhh[l] = (const float*)d_in[8] + (l - 1) * 20;
  }
  p.wih[20] = (const float*)d_in[9];   p.whh[20] = (const float*)d_in[10];
  p.bih[20] = (const float*)d_in[11];  p.bhh[20] = (const float*)d_in[12];
  for (int l = 21; l < 30; l++) {
    p.wih[l] = (const float*)d_in[13] + (l - 21) * 100;
    p.whh[l] = (const float*)d_in[14] + (l - 21) * 100;
    p.bih[l] = (const float*)d_in[15] + (l - 21) * 10;
    p.bhh[l] = (const float*)d_in[16] + (l - 21) * 10;
  }
  p.wih[30] = (const float*)d_in[17];  p.whh[30] = (const float*)d_in[18];
  p.bih[30] = (const float*)d_in[19];  p.bhh[30] = (const float*)d_in[20];
  p.out = (float*)d_out;

  rnn_fused<<<43, 1024, 0, stream>>>(p);
}